// Round 1
// baseline (498.131 us; speedup 1.0000x reference)
//
#include <hip/hip_runtime.h>

// ApplyPolicyMap: fc1 is a fixed one-hot selection matrix [5120, 1858]
// (each column j has exactly one 1.0 at row src_idx[j]).
// => out[b, j] = x_flat[b, src_idx[j]]  — a pure gather, no matmul needed.

#define FLAT   5120
#define NMOVES 1858
#define THREADS 256
#define ROWS_PER_BLOCK 8

typedef const __attribute__((address_space(1))) void* as1_cvp;
typedef __attribute__((address_space(3))) void*       as3_vp;

// Kernel 1: recover src_idx[j] from fc1 each call (inputs re-restored every
// launch; no static caching allowed). fc1 row-major [FLAT, NMOVES]; exactly
// one nonzero per column => plain writes are race-free and every idx[j] is
// written. Pure 38 MB read stream, ~6-8 us.
__global__ __launch_bounds__(256) void extract_idx_kernel(
        const float4* __restrict__ fc1_v4, int* __restrict__ idx) {
    const int total4 = (FLAT * NMOVES) / 4;  // exact
    int t = blockIdx.x * blockDim.x + threadIdx.x;
    if (t >= total4) return;
    float4 v = fc1_v4[t];
    int base = t * 4;
    if (v.x != 0.0f) { int e = base;     idx[e % NMOVES] = e / NMOVES; }
    if (v.y != 0.0f) { int e = base + 1; idx[e % NMOVES] = e / NMOVES; }
    if (v.z != 0.0f) { int e = base + 2; idx[e % NMOVES] = e / NMOVES; }
    if (v.w != 0.0f) { int e = base + 3; idx[e % NMOVES] = e / NMOVES; }
}

// Kernel 2: 8 rows per block, double-buffered async LDS staging.
// Per row: 5 global_load_lds_dwordx4 per thread (20 wave-instructions of
// 1 KB), counted vmcnt(5) so the next row's prefetch stays in flight across
// the barrier (never drain to 0 in the main loop). idx lives in LDS.
// LDS = 2*20480 + 7432 = 48.4 KB -> 3 blocks/CU, 12 waves/CU; in-flight
// load data per CU ~120 KB >> the ~9 KB needed at the per-CU HBM share.
__global__ __launch_bounds__(256) void gather_rows_kernel(
        const float* __restrict__ x, const int* __restrict__ idx,
        float* __restrict__ out, int batch) {
    __shared__ float buf[2][FLAT];     // 2 x 20 KB row double-buffer
    __shared__ int   idxs[NMOVES];     // 7.4 KB, read-only after prologue

    const int  t  = threadIdx.x;
    const int  w  = t >> 6;            // wave id 0..3 (wave-uniform)
    const long b0 = (long)blockIdx.x * ROWS_PER_BLOCK;
    if (b0 >= batch) return;
    const int rows = (batch - b0 < ROWS_PER_BLOCK) ? (int)(batch - b0)
                                                   : ROWS_PER_BLOCK;

    // Stage idx into LDS once per block (coalesced; L2-hot source).
    for (int j = t; j < NMOVES; j += THREADS) idxs[j] = idx[j];

    // Prologue: async-stage row 0 into buf[0].
    // LDS dest is wave-uniform base + lane*16 (HW rule); global src per-lane.
    {
        const char* gx = (const char*)(x + b0 * FLAT);
        char* lb = (char*)buf[0];
        #pragma unroll
        for (int i = 0; i < 5; ++i)
            __builtin_amdgcn_global_load_lds(
                (as1_cvp)(gx + ((i * 256 + t) << 4)),
                (as3_vp)(lb + (i << 12) + (w << 10)), 16, 0, 0);
    }
    __syncthreads();  // prologue-only full drain: idxs + row0 resident

    for (int r = 0; r < rows; ++r) {
        if (r + 1 < rows) {
            // Prefetch next row into the other buffer (stays in flight).
            const char* gx = (const char*)(x + (b0 + r + 1) * FLAT);
            char* lb = (char*)buf[(r + 1) & 1];
            #pragma unroll
            for (int i = 0; i < 5; ++i)
                __builtin_amdgcn_global_load_lds(
                    (as1_cvp)(gx + ((i * 256 + t) << 4)),
                    (as3_vp)(lb + (i << 12) + (w << 10)), 16, 0, 0);
            // Outstanding (oldest->newest): row r loads [5], prior stores
            // [<=4], row r+1 loads [5]. vmcnt(5) retires everything except
            // the prefetch -> row r is resident, pipeline stays primed.
            asm volatile("s_waitcnt vmcnt(5)" ::: "memory");
        } else {
            asm volatile("s_waitcnt vmcnt(0)" ::: "memory");
        }
        __builtin_amdgcn_s_barrier();        // B1: row r resident for all
        __builtin_amdgcn_sched_barrier(0);

        const float* rb = buf[r & 1];
        float* o = out + (b0 + r) * NMOVES;
        // 929 float2 stores; row base 7432 B = 0 mod 8 and j0 even -> aligned.
        for (int j0 = t * 2; j0 < NMOVES; j0 += 2 * THREADS) {
            int2 ix = *(const int2*)&idxs[j0];
            float2 v = make_float2(rb[ix.x], rb[ix.y]);
            *(float2*)(o + j0) = v;
        }
        __builtin_amdgcn_s_barrier();        // B2: buf[r&1] reads done before
        __builtin_amdgcn_sched_barrier(0);   //     iter r+1 overwrites it
    }
}

extern "C" void kernel_launch(void* const* d_in, const int* in_sizes, int n_in,
                              void* d_out, int out_size, void* d_ws, size_t ws_size,
                              hipStream_t stream) {
    const float* x   = (const float*)d_in[0];   // [16384, 80, 8, 8] fp32
    const float* fc1 = (const float*)d_in[1];   // [5120, 1858] fp32 one-hot
    float* out = (float*)d_out;                 // [16384, 1858] fp32
    int* idx = (int*)d_ws;                      // 1858 ints of scratch

    const int batch = in_sizes[0] / FLAT;       // 16384

    const int total4 = (FLAT * NMOVES) / 4;
    dim3 g1((total4 + 255) / 256), b1(256);
    extract_idx_kernel<<<g1, b1, 0, stream>>>((const float4*)fc1, idx);

    dim3 g2((batch + ROWS_PER_BLOCK - 1) / ROWS_PER_BLOCK), b2(THREADS);
    gather_rows_kernel<<<g2, b2, 0, stream>>>(x, idx, out, batch);
}

// Round 2
// 486.970 us; speedup vs baseline: 1.0229x; 1.0229x over previous
//
#include <hip/hip_runtime.h>

// ApplyPolicyMap: fc1 is a fixed one-hot selection matrix [5120, 1858]
// (each column j has exactly one 1.0 at row src_idx[j]).
// => out[b, j] = x_flat[b, src_idx[j]]  — a pure gather, no matmul needed.

#define FLAT   5120
#define NMOVES 1858
#define THREADS 256

typedef const __attribute__((address_space(1))) void* as1_cvp;
typedef __attribute__((address_space(3))) void*       as3_vp;

// Kernel 1: recover src_idx[j] from fc1 each call (inputs re-restored every
// launch; no static caching allowed). fc1 row-major [FLAT, NMOVES]; exactly
// one nonzero per column => plain writes are race-free and every idx[j] is
// written. Pure 38 MB read stream, ~6-8 us.
__global__ __launch_bounds__(256) void extract_idx_kernel(
        const float4* __restrict__ fc1_v4, int* __restrict__ idx) {
    const int total4 = (FLAT * NMOVES) / 4;  // 2,378,240 — grid covers exactly
    int t = blockIdx.x * blockDim.x + threadIdx.x;
    if (t >= total4) return;
    float4 v = fc1_v4[t];
    int base = t * 4;
    if (v.x != 0.0f) { int e = base;     idx[e % NMOVES] = e / NMOVES; }
    if (v.y != 0.0f) { int e = base + 1; idx[e % NMOVES] = e / NMOVES; }
    if (v.z != 0.0f) { int e = base + 2; idx[e % NMOVES] = e / NMOVES; }
    if (v.w != 0.0f) { int e = base + 3; idx[e % NMOVES] = e / NMOVES; }
}

// Kernel 2: one-shot block per row, max TLP. LDS = 20480 B exactly ->
// 8 blocks/CU = 32 waves/CU (full occupancy); the CU hides each block's
// DMA wait behind 7 other blocks' gather/store phases. Structure:
//   20x global_load_lds_dwordx4 (direct-to-LDS, no VGPR bounce)
//   idx pairs -> registers while DMA is in flight (L2-hot after block 0)
//   one __syncthreads() (compiler emits the vmcnt/lgkm drain)
//   4 predicated float2 gather-stores (929 pairs = 3*256 + 161)
__global__ __launch_bounds__(256) void gather_rows_kernel(
        const float* __restrict__ x, const int* __restrict__ idx,
        float* __restrict__ out) {
    __shared__ float row[FLAT];        // 20 KB, nothing else in LDS
    const int  t = threadIdx.x;
    const int  w = t >> 6;             // wave id (wave-uniform LDS base)
    const long b = blockIdx.x;

    // Async DMA: LDS dest is wave-uniform base + lane*16 (HW rule);
    // global source is per-lane. Linear layout on both sides.
    const char* gx = (const char*)(x + b * FLAT);
    char* lb = (char*)row;
    #pragma unroll
    for (int i = 0; i < 5; ++i)
        __builtin_amdgcn_global_load_lds(
            (as1_cvp)(gx + ((i * 256 + t) << 4)),
            (as3_vp)(lb + (i << 12) + (w << 10)), 16, 0, 0);

    // Prefetch idx pairs into registers; completes under the DMA shadow.
    int2 ix[4];
    #pragma unroll
    for (int k = 0; k < 4; ++k) {
        int p = t + (k << 8);          // pair index
        if (p < NMOVES / 2) ix[k] = *(const int2*)(idx + 2 * p);
    }

    __syncthreads();  // full drain: row + ix resident for all waves

    // 929 aligned float2 stores (row byte base 7432 = 0 mod 8, offsets even).
    float* o = out + b * NMOVES;
    #pragma unroll
    for (int k = 0; k < 4; ++k) {
        int p = t + (k << 8);
        if (p < NMOVES / 2)
            *(float2*)(o + 2 * p) = make_float2(row[ix[k].x], row[ix[k].y]);
    }
}

extern "C" void kernel_launch(void* const* d_in, const int* in_sizes, int n_in,
                              void* d_out, int out_size, void* d_ws, size_t ws_size,
                              hipStream_t stream) {
    const float* x   = (const float*)d_in[0];   // [16384, 80, 8, 8] fp32
    const float* fc1 = (const float*)d_in[1];   // [5120, 1858] fp32 one-hot
    float* out = (float*)d_out;                 // [16384, 1858] fp32
    int* idx = (int*)d_ws;                      // 1858 ints of scratch

    const int batch = in_sizes[0] / FLAT;       // 16384

    const int total4 = (FLAT * NMOVES) / 4;
    dim3 g1((total4 + 255) / 256), b1(256);
    extract_idx_kernel<<<g1, b1, 0, stream>>>((const float4*)fc1, idx);

    dim3 g2(batch), b2(THREADS);
    gather_rows_kernel<<<g2, b2, 0, stream>>>(x, idx, out);
}